// Round 10
// baseline (1821.797 us; speedup 1.0000x reference)
//
#include <hip/hip_runtime.h>

// Att_RNN_GRU: B=128, T=1024, I=128, H=256 (3H=768), A=40
// Phase 1: gx = x @ W_ih^T + b_ih (+b_hh for r,z)  -> f16 [B*T,768]  (MFMA GEMM)
// Phase 2: GRU recurrence, 1 block/batch, 512 thr (8 waves, 2/SIMD):
//          thread (rg=tid>>3, ks=tid&7) owns 12 rows {4rg+j, 256+4rg+j,
//          512+4rg+j | j=0..3} over k-slice [32ks,32ks+32) f16. 12x reuse of
//          each h dword -> LDS replication 32KB/step (was 128KB). Reduce over
//          ks: xor1/xor2 DPP + xor4 ds_swizzle. Gates on ks==0 lanes only.
//          One raw barrier/step; distance-2 x prefetch; h_t overwrites gx row.
// Phase 3a: s[b,t] = wu . tanh(wv_W @ out + wv_b)   (outs = gx rows, stride 768)
// Phase 3b: softmax over t, context, out = context @ h2o_W^T + b
//
// Workspace: s @0 (512KB), Wp @524288 (384KB), gx @917504 (192MB) = 202.2MB

#define B_ 128
#define T_ 1024
#define I_ 128
#define H_ 256
#define G_ 768
#define A_ 40

typedef _Float16 f16;
typedef _Float16 f16x2 __attribute__((ext_vector_type(2)));
typedef _Float16 f16x8 __attribute__((ext_vector_type(8)));
typedef float    f32x4 __attribute__((ext_vector_type(4)));

__device__ __forceinline__ float fdot2(unsigned a, unsigned b, float c){
#if __has_builtin(__builtin_amdgcn_fdot2)
  return __builtin_amdgcn_fdot2(__builtin_bit_cast(f16x2, a),
                                __builtin_bit_cast(f16x2, b), c, false);
#else
  f16x2 av = __builtin_bit_cast(f16x2, a), bv = __builtin_bit_cast(f16x2, b);
  return c + (float)av.x * (float)bv.x + (float)av.y * (float)bv.y;
#endif
}

__device__ __forceinline__ float2 h2f(unsigned u){
  f16x2 h = __builtin_bit_cast(f16x2, u);
  return make_float2((float)h.x, (float)h.y);
}
__device__ __forceinline__ unsigned f2h2(float a, float b){
  f16x2 h; h.x = (f16)a; h.y = (f16)b;
  return __builtin_bit_cast(unsigned, h);
}
__device__ __forceinline__ float rcp_(float x){ return __builtin_amdgcn_rcpf(x); }
__device__ __forceinline__ float sigm_(float x){ return rcp_(1.f + __expf(-x)); }
__device__ __forceinline__ float tanh_(float x){ return 1.f - 2.f * rcp_(__expf(2.f * x) + 1.f); }

// partner value via DPP quad_perm (VALU pipe); PAT is a compile-time constant
template<int PAT>
__device__ __forceinline__ float dppf(float x){
  return __builtin_bit_cast(float,
      __builtin_amdgcn_update_dpp(0, __builtin_bit_cast(int, x), PAT, 0xF, 0xF, true));
}

// ---------------------------------------------------------------- prep W_hh
// k_gru thread `col` (rg=col>>3, ks=col&7), w-dword dd = (c*4+j)*16 + d:
// Wp[dd*512 + col] = f16 pair of W[256c + 4rg + j][32ks + 2d .. +1]
__global__ __launch_bounds__(256) void k_prep_w(const float* __restrict__ W,
                                                unsigned* __restrict__ Wp){
  int idx = blockIdx.x * 256 + threadIdx.x;      // 0 .. 98303
  int dd  = idx >> 9;                            // 0..191
  int col = idx & 511;
  int c = dd >> 6, j = (dd >> 4) & 3, d = dd & 15;
  int rg = col >> 3, ks = col & 7;
  int row = 256 * c + 4 * rg + j;
  int k = 32 * ks + 2 * d;
  Wp[(size_t)dd * 512 + col] = f2h2(W[row * 256 + k], W[row * 256 + k + 1]);
}

// ---------------------------------------------------------------- phase 1
// MFMA GEMM: gx[m][n] = sum_k x[m][k]*W_ih[n][k] + b_ih[n] + (n<512 ? b_hh[n]:0)
__global__ __launch_bounds__(256) void k_gx(const float* __restrict__ x,
                                            const float* __restrict__ wih,
                                            const float* __restrict__ bih,
                                            const float* __restrict__ bhh,
                                            f16* __restrict__ gx){
  __shared__ __align__(16) f16 XA[128 * 128];   // [m][k], byte ^= (m&7)<<4
  __shared__ __align__(16) f16 XB[64 * 128];    // [n][k], same swizzle
  const int tid = threadIdx.x;
  const int m0 = blockIdx.x * 128, n0 = blockIdx.y * 64;

  #pragma unroll
  for (int u = 0; u < 16; ++u){
    int idx = tid + 256 * u;
    int row = idx >> 5, k4 = idx & 31;
    float4 v = *(const float4*)(x + (size_t)(m0 + row) * I_ + k4 * 4);
    unsigned byte = (unsigned)(row * 256 + k4 * 8) ^ ((row & 7) << 4);
    *(uint2*)((char*)XA + byte) = make_uint2(f2h2(v.x, v.y), f2h2(v.z, v.w));
  }
  #pragma unroll
  for (int u = 0; u < 8; ++u){
    int idx = tid + 256 * u;
    int row = idx >> 5, k4 = idx & 31;
    float4 v = *(const float4*)(wih + (size_t)(n0 + row) * I_ + k4 * 4);
    unsigned byte = (unsigned)(row * 256 + k4 * 8) ^ ((row & 7) << 4);
    *(uint2*)((char*)XB + byte) = make_uint2(f2h2(v.x, v.y), f2h2(v.z, v.w));
  }
  __syncthreads();

  const int l = tid & 63, w = tid >> 6;
  const int q = l >> 4, m16 = l & 15;
  f32x4 acc[2][4];
  #pragma unroll
  for (int i = 0; i < 2; ++i)
    #pragma unroll
    for (int nt = 0; nt < 4; ++nt) acc[i][nt] = (f32x4){0.f, 0.f, 0.f, 0.f};

  #pragma unroll
  for (int kt = 0; kt < 4; ++kt){
    f16x8 af[2];
    #pragma unroll
    for (int i = 0; i < 2; ++i){
      int row = (2 * w + i) * 16 + m16;
      unsigned byte = (unsigned)(row * 256 + kt * 64 + q * 16) ^ ((row & 7) << 4);
      af[i] = *(const f16x8*)((const char*)XA + byte);
    }
    #pragma unroll
    for (int nt = 0; nt < 4; ++nt){
      int row = nt * 16 + m16;
      unsigned byte = (unsigned)(row * 256 + kt * 64 + q * 16) ^ ((row & 7) << 4);
      f16x8 bv = *(const f16x8*)((const char*)XB + byte);
      acc[0][nt] = __builtin_amdgcn_mfma_f32_16x16x32_f16(af[0], bv, acc[0][nt], 0, 0, 0);
      acc[1][nt] = __builtin_amdgcn_mfma_f32_16x16x32_f16(af[1], bv, acc[1][nt], 0, 0, 0);
    }
  }

  float bn[4];
  #pragma unroll
  for (int nt = 0; nt < 4; ++nt){
    int n = n0 + nt * 16 + m16;
    bn[nt] = bih[n] + (n < 512 ? bhh[n] : 0.f);
  }

  __syncthreads();
  f16* ST = XA;                                  // reuse as [128][72]
  #pragma unroll
  for (int i = 0; i < 2; ++i)
    #pragma unroll
    for (int nt = 0; nt < 4; ++nt)
      #pragma unroll
      for (int j = 0; j < 4; ++j){
        int row = (2 * w + i) * 16 + 4 * q + j;
        ST[row * 72 + nt * 16 + m16] = (f16)(acc[i][nt][j] + bn[nt]);
      }
  __syncthreads();
  #pragma unroll
  for (int u = 0; u < 4; ++u){
    int idx = tid + 256 * u;
    int row = idx >> 3, c = idx & 7;
    uint4 v = *(const uint4*)(ST + row * 72 + c * 8);
    *(uint4*)(gx + (size_t)(m0 + row) * G_ + n0 + c * 8) = v;
  }
}

// ---------------------------------------------------------------- phase 2
// 128 blocks x 512 threads (8 waves, 2/SIMD).
__global__ __launch_bounds__(512, 2) void k_gru(const unsigned* __restrict__ Wp,
                                                unsigned* __restrict__ gx,
                                                const float* __restrict__ bhh){
  // h buffers: 8 chunks of 16 payload dwords, stride 20 (bank-staggered, 16B-aligned)
  __shared__ __align__(16) unsigned hb[2][160];
  const int tid = threadIdx.x;
  const int rg = tid >> 3, ks = tid & 7;
  const int b = blockIdx.x;

  unsigned w[192];
  #pragma unroll
  for (int d = 0; d < 192; ++d) w[d] = Wp[(size_t)d * 512 + tid];

  float bn[4];
  #pragma unroll
  for (int j = 0; j < 4; ++j) bn[j] = bhh[512 + 4 * rg + j];

  float hprev[4] = {0.f, 0.f, 0.f, 0.f};
  if (tid < 160){ hb[0][tid] = 0u; }

  f16* gxp = (f16*)gx + (size_t)b * T_ * G_;

  // x pipeline (ks==0 lanes only), distance 2
  uint2 xr0 = {0,0}, xz0 = {0,0}, xn0 = {0,0};
  uint2 xr1 = {0,0}, xz1 = {0,0}, xn1 = {0,0};
  if (ks == 0){
    xr0 = *(const uint2*)(gxp + 4 * rg);
    xz0 = *(const uint2*)(gxp + 256 + 4 * rg);
    xn0 = *(const uint2*)(gxp + 512 + 4 * rg);
    xr1 = *(const uint2*)(gxp + G_ + 4 * rg);
    xz1 = *(const uint2*)(gxp + G_ + 256 + 4 * rg);
    xn1 = *(const uint2*)(gxp + G_ + 512 + 4 * rg);
  }
  __syncthreads();

  const int rbase = 20 * ks;                     // my chunk (dwords)
  const int wdw = 2 * rg + 4 * (rg >> 3);        // my h write addr (even dword)
  int cur = 0;
  for (int t = 0; t < T_; ++t){
    // read my 16-dword k-slice: 4 x b128, bank-staggered across ks
    uint4 h0 = *(const uint4*)&hb[cur][rbase + 0];
    uint4 h1 = *(const uint4*)&hb[cur][rbase + 4];
    uint4 h2 = *(const uint4*)&hb[cur][rbase + 8];
    uint4 h3 = *(const uint4*)&hb[cur][rbase + 12];

    float s[12];
    #pragma unroll
    for (int q = 0; q < 12; ++q) s[q] = 0.f;
    #pragma unroll
    for (int q = 0; q < 12; ++q){
      const unsigned* wq = &w[q * 16];
      s[q] = fdot2(wq[0],  h0.x, s[q]); s[q] = fdot2(wq[1],  h0.y, s[q]);
      s[q] = fdot2(wq[2],  h0.z, s[q]); s[q] = fdot2(wq[3],  h0.w, s[q]);
      s[q] = fdot2(wq[4],  h1.x, s[q]); s[q] = fdot2(wq[5],  h1.y, s[q]);
      s[q] = fdot2(wq[6],  h1.z, s[q]); s[q] = fdot2(wq[7],  h1.w, s[q]);
      s[q] = fdot2(wq[8],  h2.x, s[q]); s[q] = fdot2(wq[9],  h2.y, s[q]);
      s[q] = fdot2(wq[10], h2.z, s[q]); s[q] = fdot2(wq[11], h2.w, s[q]);
      s[q] = fdot2(wq[12], h3.x, s[q]); s[q] = fdot2(wq[13], h3.y, s[q]);
      s[q] = fdot2(wq[14], h3.z, s[q]); s[q] = fdot2(wq[15], h3.w, s[q]);
    }
    // reduce over ks: ^1,^2 via DPP (VALU), ^4 via ds_swizzle
    #pragma unroll
    for (int q = 0; q < 12; ++q){
      float x = s[q];
      x += dppf<0xB1>(x);                        // quad_perm 1,0,3,2 (xor 1)
      x += dppf<0x4E>(x);                        // quad_perm 2,3,0,1 (xor 2)
      x += __builtin_bit_cast(float,
            __builtin_amdgcn_ds_swizzle(__builtin_bit_cast(int, x), 0x101F));
      s[q] = x;
    }

    if (ks == 0){
      // prefetch t+2 x-terms (wrapped index; garbage never consumed)
      const f16* nx = gxp + (size_t)((t + 2) & (T_ - 1)) * G_;
      uint2 xr2 = *(const uint2*)(nx + 4 * rg);
      uint2 xz2 = *(const uint2*)(nx + 256 + 4 * rg);
      uint2 xn2 = *(const uint2*)(nx + 512 + 4 * rg);

      float2 ra = h2f(xr0.x), rb = h2f(xr0.y);
      float2 za = h2f(xz0.x), zb = h2f(xz0.y);
      float2 na = h2f(xn0.x), nb = h2f(xn0.y);
      float xrj[4] = {ra.x, ra.y, rb.x, rb.y};
      float xzj[4] = {za.x, za.y, zb.x, zb.y};
      float xnj[4] = {na.x, na.y, nb.x, nb.y};
      float hh[4];
      #pragma unroll
      for (int j = 0; j < 4; ++j){
        float r = sigm_(xrj[j] + s[j]);          // b_hh(r,z) folded into gx
        float z = sigm_(xzj[j] + s[4 + j]);
        float n = tanh_(xnj[j] + r * (s[8 + j] + bn[j]));
        float h = (1.f - z) * n + z * hprev[j];
        hprev[j] = h;
        hh[j] = h;
      }
      uint2 hw = make_uint2(f2h2(hh[0], hh[1]), f2h2(hh[2], hh[3]));
      *(uint2*)&hb[cur ^ 1][wdw] = hw;           // h for next step (chunked layout)
      *(uint2*)(gxp + (size_t)t * G_ + 4 * rg) = hw;  // overwrite consumed gx row
      xr0 = xr1; xz0 = xz1; xn0 = xn1;
      xr1 = xr2; xz1 = xz2; xn1 = xn2;
    }

    // raw barrier: commit LDS writes; vmcnt not drained (prefetch/stores fly)
    asm volatile("s_waitcnt lgkmcnt(0)" ::: "memory");
    __builtin_amdgcn_s_barrier();
    asm volatile("" ::: "memory");
    cur ^= 1;
  }
}

// ---------------------------------------------------------------- phase 3a
__global__ __launch_bounds__(256) void k_score(const f16* __restrict__ outs,
                                               const float* __restrict__ wvW,
                                               const float* __restrict__ wvb,
                                               const float* __restrict__ wu,
                                               float* __restrict__ s){
  __shared__ uint4 OT[32 * 33];
  __shared__ float WV[A_ * 260];
  const int tid = threadIdx.x;
  const int m0 = blockIdx.x * 32;

  #pragma unroll
  for (int u = 0; u < 4; ++u){
    int idx = tid + 256 * u;
    int row = idx >> 5, col = idx & 31;
    OT[row * 33 + col] = *(const uint4*)(outs + (size_t)(m0 + row) * G_ + col * 8);
  }
  #pragma unroll
  for (int u = 0; u < 10; ++u){
    int f = tid + 256 * u;
    int a = f >> 6, k4 = f & 63;
    float4 v = *(const float4*)(wvW + a * 256 + k4 * 4);
    *(float4*)(WV + a * 260 + k4 * 4) = v;
  }
  __syncthreads();

  const int m = tid >> 3, aq = tid & 7;
  float acc[5] = {0.f, 0.f, 0.f, 0.f, 0.f};
  for (int i = 0; i < 32; ++i){
    uint4 oc = OT[m * 33 + i];
    float2 o01 = h2f(oc.x), o23 = h2f(oc.y), o45 = h2f(oc.z), o67 = h2f(oc.w);
    #pragma unroll
    for (int sa = 0; sa < 5; ++sa){
      int a = aq + sa * 8;
      const float* wr = &WV[a * 260 + i * 8];
      float4 w0 = *(const float4*)wr;
      float4 w1 = *(const float4*)(wr + 4);
      acc[sa] += o01.x*w0.x + o01.y*w0.y + o23.x*w0.z + o23.y*w0.w
               + o45.x*w1.x + o45.y*w1.y + o67.x*w1.z + o67.y*w1.w;
    }
  }
  float sp = 0.f;
  #pragma unroll
  for (int sa = 0; sa < 5; ++sa){
    int a = aq + sa * 8;
    sp += wu[a] * tanh_(acc[sa] + wvb[a]);
  }
  sp += __shfl_xor(sp, 1);
  sp += __shfl_xor(sp, 2);
  sp += __shfl_xor(sp, 4);
  if (aq == 0) s[m0 + m] = sp;
}

// ---------------------------------------------------------------- phase 3b
__global__ __launch_bounds__(256) void k_ctx(const f16* __restrict__ outs,
                                             const float* __restrict__ s,
                                             const float* __restrict__ h2oW,
                                             const float* __restrict__ h2ob,
                                             float* __restrict__ out){
  __shared__ float AL[T_];
  __shared__ float red[8];
  const int tid = threadIdx.x;
  const int b = blockIdx.x;
  const float* sb = s + (size_t)b * T_;

  float v0 = sb[tid], v1 = sb[tid + 256], v2 = sb[tid + 512], v3 = sb[tid + 768];
  float mx = fmaxf(fmaxf(v0, v1), fmaxf(v2, v3));
  #pragma unroll
  for (int msk = 1; msk < 64; msk <<= 1) mx = fmaxf(mx, __shfl_xor(mx, msk));
  if ((tid & 63) == 0) red[tid >> 6] = mx;
  __syncthreads();
  mx = fmaxf(fmaxf(red[0], red[1]), fmaxf(red[2], red[3]));

  float e0 = __expf(v0 - mx), e1 = __expf(v1 - mx), e2 = __expf(v2 - mx), e3 = __expf(v3 - mx);
  float zs = e0 + e1 + e2 + e3;
  #pragma unroll
  for (int msk = 1; msk < 64; msk <<= 1) zs += __shfl_xor(zs, msk);
  if ((tid & 63) == 0) red[4 + (tid >> 6)] = zs;
  __syncthreads();
  float invZ = 1.f / (red[4] + red[5] + red[6] + red[7]);
  AL[tid] = e0 * invZ; AL[tid + 256] = e1 * invZ;
  AL[tid + 512] = e2 * invZ; AL[tid + 768] = e3 * invZ;
  __syncthreads();

  const f16* ob = outs + (size_t)b * T_ * G_;
  float acc = 0.f;
  for (int t = 0; t < T_; t += 4){
    acc += AL[t + 0] * (float)ob[(size_t)(t + 0) * G_ + tid];
    acc += AL[t + 1] * (float)ob[(size_t)(t + 1) * G_ + tid];
    acc += AL[t + 2] * (float)ob[(size_t)(t + 2) * G_ + tid];
    acc += AL[t + 3] * (float)ob[(size_t)(t + 3) * G_ + tid];
  }
  __syncthreads();
  float val = acc * h2oW[tid];
  #pragma unroll
  for (int msk = 1; msk < 64; msk <<= 1) val += __shfl_xor(val, msk);
  if ((tid & 63) == 0) red[tid >> 6] = val;
  __syncthreads();
  if (tid == 0) out[b] = red[0] + red[1] + red[2] + red[3] + h2ob[0];
}

// ---------------------------------------------------------------- launch
extern "C" void kernel_launch(void* const* d_in, const int* in_sizes, int n_in,
                              void* d_out, int out_size, void* d_ws, size_t ws_size,
                              hipStream_t stream){
  const float* x    = (const float*)d_in[0];
  const float* wih  = (const float*)d_in[1];
  const float* whh  = (const float*)d_in[2];
  const float* bih  = (const float*)d_in[3];
  const float* bhh  = (const float*)d_in[4];
  const float* wvW  = (const float*)d_in[5];
  const float* wvb  = (const float*)d_in[6];
  const float* wu   = (const float*)d_in[7];
  const float* h2oW = (const float*)d_in[8];
  const float* h2ob = (const float*)d_in[9];
  float* out = (float*)d_out;

  char* ws = (char*)d_ws;
  float*    s  = (float*)ws;                      //     524,288 B
  unsigned* Wp = (unsigned*)(ws + 524288);        //     393,216 B
  unsigned* gx = (unsigned*)(ws + 917504);        // 201,326,592 B

  k_prep_w<<<384, 256, 0, stream>>>(whh, Wp);
  k_gx<<<dim3((B_ * T_) / 128, G_ / 64), 256, 0, stream>>>(x, wih, bih, bhh, (f16*)gx);
  k_gru<<<B_, 512, 0, stream>>>(Wp, gx, bhh);
  k_score<<<(B_ * T_) / 32, 256, 0, stream>>>((const f16*)gx, wvW, wvb, wu, s);
  k_ctx<<<B_, 256, 0, stream>>>((const f16*)gx, s, h2oW, h2ob, out);
}